// Round 14
// baseline (181.673 us; speedup 1.0000x reference)
//
#include <hip/hip_runtime.h>
#include <math.h>

#define LN_EPS 1e-3f

typedef __attribute__((ext_vector_type(8))) short short8;
typedef __attribute__((ext_vector_type(4))) float floatx4;

__device__ __forceinline__ float silu_f(float x) { return x / (1.f + expf(-x)); }

__device__ __forceinline__ int mism1(float a, float s) {
    unsigned ua = __float_as_uint(a);
    unsigned ub = __float_as_uint(a + s);
    return (int)((ua ^ ub) >> 31);
}

__device__ __forceinline__ short f2bf(float f) {
    unsigned u = __float_as_uint(f);
    unsigned r = (u + 0x7FFFu + ((u >> 16) & 1u)) >> 16;
    return (short)r;
}

__device__ __forceinline__ unsigned pk2bf(float a, float b) {
    return (unsigned)(unsigned short)f2bf(a) | ((unsigned)(unsigned short)f2bf(b) << 16);
}

// ---------------- Kernel 0: swizzle conv1 + conv2 weights into B-fragment bf16
// w1s[kc(8)][ks(10)][nt(8)][lane(64)][j(8)]  (327,680)
// w2s[ks(12)][nt(64)][lane(64)][j(8)]        (393,216)
__global__ __launch_bounds__(256) void k_prep(
    const float* __restrict__ w1,   // (5,512,128)
    const float* __restrict__ w2,   // (3,128,1024)
    short* __restrict__ w1s,
    short* __restrict__ w2s)
{
    int tid = blockIdx.x * 256 + threadIdx.x;
    if (tid < 327680) {
        int j    = tid & 7;
        int lane = (tid >> 3) & 63;
        int nt   = (tid >> 9) & 7;
        int ks   = (tid >> 12) % 10;
        int kc   = tid / 40960;
        int kw = ks >> 1;
        int ci = kc * 64 + (ks & 1) * 32 + ((lane >> 4) & 3) * 8 + j;
        int n  = nt * 16 + (lane & 15);
        w1s[tid] = f2bf(w1[((size_t)(kw * 512 + ci)) * 128 + n]);
    } else {
        int t = tid - 327680;
        if (t < 393216) {
            int j    = t & 7;
            int lane = (t >> 3) & 63;
            int nt   = (t >> 9) & 63;
            int ks   = t >> 15;                 // 0..11
            int k  = ks * 32 + ((lane >> 4) & 3) * 8 + j;   // 0..383
            int kw = k >> 7;
            int ci = k & 127;
            int n  = nt * 16 + (lane & 15);
            w2s[t] = f2bf(w2[((size_t)(kw * 128 + ci)) * 1024 + n]);
        }
    }
}

// ---------------- Kernel 1: conv1 MFMA + bias + LN1(128) + SiLU -> h1 bf16
// grid = 200 blocks (16 pos each), 256 threads (4 waves, 2 n-tiles each).
// Double-buffered LDS staging: chunk kc+1 global loads issue before MFMA(kc),
// packed uint2 bf16 LDS writes after; one barrier per chunk.
__global__ __launch_bounds__(256) void k_conv1m(
    const float* __restrict__ values,   // (4,1920,512)
    const float* __restrict__ symbols,  // (1920,512)
    const short* __restrict__ w1s,
    const float* __restrict__ b1,
    const float* __restrict__ g1,
    const float* __restrict__ bt1,
    short* __restrict__ h1)             // (3200,128) bf16
{
    int mt  = blockIdx.x;               // 0..199
    int seq = mt / 40;
    int tl  = mt % 40;
    const float* x = (seq < 4) ? (values + (size_t)seq * 1920 * 512) : symbols;
    int p0 = 3 * (tl * 16) - 1;

    __shared__ short xs[2][50 * 72];
    __shared__ float red[4][4][4][2];

    int tid  = threadIdx.x;
    int lane = tid & 63, w = tid >> 6;
    int quad = lane >> 4, mrow = lane & 15;

    // prologue: stage chunk 0
    for (int idx = tid; idx < 800; idx += 256) {
        int r = idx >> 4, g = idx & 15;
        int gp = p0 + r;
        float4 v = make_float4(0.f, 0.f, 0.f, 0.f);
        if (gp >= 0 && gp < 1920)
            v = *(const float4*)(x + (size_t)gp * 512 + 4 * g);
        uint2 p;
        p.x = pk2bf(v.x, v.y);
        p.y = pk2bf(v.z, v.w);
        *(uint2*)(xs[0] + r * 72 + 4 * g) = p;
    }

    floatx4 acc[2];
    acc[0] = (floatx4){0.f, 0.f, 0.f, 0.f};
    acc[1] = (floatx4){0.f, 0.f, 0.f, 0.f};

    for (int kc = 0; kc < 8; kc++) {
        // issue next chunk's global loads (in flight across the MFMA loop)
        float4 nv[4];
        if (kc < 7) {
            int cnt = 0;
            for (int idx = tid; idx < 800; idx += 256, cnt++) {
                int r = idx >> 4, g = idx & 15;
                int gp = p0 + r;
                nv[cnt] = make_float4(0.f, 0.f, 0.f, 0.f);
                if (gp >= 0 && gp < 1920)
                    nv[cnt] = *(const float4*)(x + (size_t)gp * 512 + (kc + 1) * 64 + 4 * g);
            }
        }

        __syncthreads();   // buffer kc&1 fully written (prologue / prev iter)

        const short* xb = xs[kc & 1];
        #pragma unroll
        for (int ks = 0; ks < 10; ks++) {
            int kw  = ks >> 1;
            int ci0 = (ks & 1) * 32;
            short8 a = *(const short8*)(xb + (3 * mrow + kw) * 72 + ci0 + quad * 8);
            #pragma unroll
            for (int ni = 0; ni < 2; ni++) {
                short8 b = *(const short8*)(w1s +
                    ((((size_t)kc * 10 + ks) * 8 + (w * 2 + ni)) * 64 + lane) * 8);
                acc[ni] = __builtin_amdgcn_mfma_f32_16x16x32_bf16(a, b, acc[ni], 0, 0, 0);
            }
        }

        // convert + write next chunk into the other buffer
        if (kc < 7) {
            short* xn = xs[(kc + 1) & 1];
            int cnt = 0;
            for (int idx = tid; idx < 800; idx += 256, cnt++) {
                int r = idx >> 4, g = idx & 15;
                uint2 p;
                p.x = pk2bf(nv[cnt].x, nv[cnt].y);
                p.y = pk2bf(nv[cnt].z, nv[cnt].w);
                *(uint2*)(xn + r * 72 + 4 * g) = p;
            }
        }
    }

    float b1v[2], g1v[2], btv[2];
    #pragma unroll
    for (int ni = 0; ni < 2; ni++) {
        int co = w * 32 + ni * 16 + mrow;
        b1v[ni] = b1[co]; g1v[ni] = g1[co]; btv[ni] = bt1[co];
    }

    float s1[4] = {0.f, 0.f, 0.f, 0.f}, s2[4] = {0.f, 0.f, 0.f, 0.f};
    #pragma unroll
    for (int ni = 0; ni < 2; ni++)
        #pragma unroll
        for (int r = 0; r < 4; r++) {
            float v = acc[ni][r] + b1v[ni];
            acc[ni][r] = v;
            s1[r] += v; s2[r] += v * v;
        }
    #pragma unroll
    for (int m = 8; m >= 1; m >>= 1) {
        #pragma unroll
        for (int r = 0; r < 4; r++) {
            s1[r] += __shfl_xor(s1[r], m, 64);
            s2[r] += __shfl_xor(s2[r], m, 64);
        }
    }
    if (mrow == 0) {
        #pragma unroll
        for (int r = 0; r < 4; r++) { red[w][quad][r][0] = s1[r]; red[w][quad][r][1] = s2[r]; }
    }
    __syncthreads();

    #pragma unroll
    for (int r = 0; r < 4; r++) {
        float S1 = red[0][quad][r][0] + red[1][quad][r][0]
                 + red[2][quad][r][0] + red[3][quad][r][0];
        float S2 = red[0][quad][r][1] + red[1][quad][r][1]
                 + red[2][quad][r][1] + red[3][quad][r][1];
        float mean = S1 * (1.f / 128.f);
        float var  = S2 * (1.f / 128.f) - mean * mean;
        float rs   = rsqrtf(var + LN_EPS);
        int row = seq * 640 + tl * 16 + quad * 4 + r;
        #pragma unroll
        for (int ni = 0; ni < 2; ni++) {
            float o = silu_f((acc[ni][r] - mean) * rs * g1v[ni] + btv[ni]);
            h1[(size_t)row * 128 + w * 32 + ni * 16 + mrow] = f2bf(o);
        }
    }
}

// ---------------- Kernel 2: conv2 MFMA (16 pos x 1024 co) + LN2 + SiLU -> vp/sp
// grid = 40 blocks, 256 threads (4 waves, 16 n-tiles each).
__global__ __launch_bounds__(256) void k_conv2m(
    const short* __restrict__ h1,    // (3200,128) bf16
    const short* __restrict__ w2s,
    const float* __restrict__ b2,
    const float* __restrict__ g2,
    const float* __restrict__ bt2,
    float* __restrict__ vp,          // (512,1024)
    float* __restrict__ sp)          // (128,1024)
{
    int blk  = blockIdx.x;           // 0..39
    int pos0 = blk * 16;
    int seq  = pos0 >> 7;
    int lcl0 = pos0 & 127;
    int row0 = seq * 640 + 5 * lcl0;

    __shared__ short xa[78 * 136];
    __shared__ float red[4][4][4][2];

    int tid = threadIdx.x;
    int lane = tid & 63, w = tid >> 6;
    int quad = lane >> 4, mrow = lane & 15;

    for (int idx = tid; idx < 78 * 16; idx += 256) {
        int r = idx >> 4, g = idx & 15;
        *(short8*)(xa + r * 136 + g * 8) =
            *(const short8*)(h1 + (size_t)(row0 + r) * 128 + g * 8);
    }
    __syncthreads();

    floatx4 acc[16];
    #pragma unroll
    for (int nt = 0; nt < 16; nt++) acc[nt] = (floatx4){0.f, 0.f, 0.f, 0.f};

    #pragma unroll 3
    for (int ks = 0; ks < 12; ks++) {
        int kw  = ks >> 2;
        int ci0 = (ks & 3) * 32;
        short8 a = *(const short8*)(xa + (5 * mrow + kw) * 136 + ci0 + quad * 8);
        #pragma unroll
        for (int nt = 0; nt < 16; nt++) {
            short8 b = *(const short8*)(w2s +
                (((size_t)ks * 64 + w * 16 + nt) * 64 + lane) * 8);
            acc[nt] = __builtin_amdgcn_mfma_f32_16x16x32_bf16(a, b, acc[nt], 0, 0, 0);
        }
    }

    float b2v[16], g2v[16], btv[16];
    #pragma unroll
    for (int nt = 0; nt < 16; nt++) {
        int co = w * 256 + nt * 16 + mrow;
        b2v[nt] = b2[co]; g2v[nt] = g2[co]; btv[nt] = bt2[co];
    }

    float s1[4] = {0.f, 0.f, 0.f, 0.f}, s2[4] = {0.f, 0.f, 0.f, 0.f};
    #pragma unroll
    for (int nt = 0; nt < 16; nt++)
        #pragma unroll
        for (int r = 0; r < 4; r++) {
            float v = acc[nt][r] + b2v[nt];
            acc[nt][r] = v;
            s1[r] += v; s2[r] += v * v;
        }
    #pragma unroll
    for (int m = 8; m >= 1; m >>= 1) {
        #pragma unroll
        for (int r = 0; r < 4; r++) {
            s1[r] += __shfl_xor(s1[r], m, 64);
            s2[r] += __shfl_xor(s2[r], m, 64);
        }
    }
    if (mrow == 0) {
        #pragma unroll
        for (int r = 0; r < 4; r++) { red[w][quad][r][0] = s1[r]; red[w][quad][r][1] = s2[r]; }
    }
    __syncthreads();

    float mean[4], rs[4];
    #pragma unroll
    for (int r = 0; r < 4; r++) {
        float S1 = red[0][quad][r][0] + red[1][quad][r][0]
                 + red[2][quad][r][0] + red[3][quad][r][0];
        float S2 = red[0][quad][r][1] + red[1][quad][r][1]
                 + red[2][quad][r][1] + red[3][quad][r][1];
        mean[r] = S1 * (1.f / 1024.f);
        float var = S2 * (1.f / 1024.f) - mean[r] * mean[r];
        rs[r] = rsqrtf(var + LN_EPS);
    }

    float* obase = (pos0 < 512) ? (vp + (size_t)pos0 * 1024)
                                : (sp + (size_t)(pos0 - 512) * 1024);
    #pragma unroll
    for (int nt = 0; nt < 16; nt++) {
        int co = w * 256 + nt * 16 + mrow;
        #pragma unroll
        for (int r = 0; r < 4; r++) {
            float o = silu_f((acc[nt][r] - mean[r]) * rs[r] * g2v[nt] + btv[nt]);
            obase[((size_t)(quad * 4 + r)) * 1024 + co] = o;
        }
    }
}

// ---------------- Kernel 3: fused attention (counts + softmax + einsum + SiLU)
// grid = 4b * 64 jpair = 256 blocks, 512 threads (8 waves).
// softmax: S in [-1,1] so exp(S) is safe without max subtraction.
__global__ __launch_bounds__(512) void k_attn(
    const float* __restrict__ vp,   // (512,1024)
    const float* __restrict__ sp,   // (128,1024)
    float* __restrict__ O)          // (4,128,1024)
{
    int b  = blockIdx.x >> 6;
    int j0 = (blockIdx.x & 63) * 2;
    int tid = threadIdx.x, lane = tid & 63, wv = tid >> 6;

    __shared__ int   cc[4][128][2];
    __shared__ float sc0[128], sc1[128];
    __shared__ float reds[2][8];

    // phase A: mismatch counts; thread = (i = tid&127, sub = tid>>7 covers 256 d)
    {
        int i = tid & 127, sub = tid >> 7;
        int d0 = sub * 256;
        const float* vrow = vp + ((size_t)(b * 128 + i)) * 1024 + d0;
        const float* s0r  = sp + (size_t)j0 * 1024 + d0;
        const float* s1r  = s0r + 1024;
        int m0 = 0, m1 = 0;
        #pragma unroll 8
        for (int k = 0; k < 64; k++) {
            float4 v  = *(const float4*)(vrow + 4 * k);
            float4 s0 = *(const float4*)(s0r + 4 * k);
            float4 s1 = *(const float4*)(s1r + 4 * k);
            m0 += mism1(v.x, s0.x) + mism1(v.y, s0.y) + mism1(v.z, s0.z) + mism1(v.w, s0.w);
            m1 += mism1(v.x, s1.x) + mism1(v.y, s1.y) + mism1(v.z, s1.z) + mism1(v.w, s1.w);
        }
        cc[sub][i][0] = m0;
        cc[sub][i][1] = m1;
    }
    __syncthreads();

    // phase B: softmax over i=128 for both j's, no max subtraction (S in [-1,1])
    float e0 = 0.f, e1 = 0.f;
    if (tid < 128) {
        int c0 = cc[0][tid][0] + cc[1][tid][0] + cc[2][tid][0] + cc[3][tid][0];
        int c1 = cc[0][tid][1] + cc[1][tid][1] + cc[2][tid][1] + cc[3][tid][1];
        e0 = expf(1.f - (float)c0 * (2.f / 1024.f));
        e1 = expf(1.f - (float)c1 * (2.f / 1024.f));
    }
    float t0 = e0, t1 = e1;
    #pragma unroll
    for (int m = 32; m >= 1; m >>= 1) {
        t0 += __shfl_xor(t0, m, 64);
        t1 += __shfl_xor(t1, m, 64);
    }
    if (lane == 0) { reds[0][wv] = t0; reds[1][wv] = t1; }
    __syncthreads();
    float tot0 = reds[0][0] + reds[0][1];
    float tot1 = reds[1][0] + reds[1][1];
    if (tid < 128) { sc0[tid] = e0 / tot0; sc1[tid] = e1 / tot1; }
    __syncthreads();

    // phase C: einsum + SiLU; thread = (jj = tid>>8, dloc = tid&255)
    {
        int jj   = tid >> 8;
        int dloc = tid & 255;
        int dd   = 4 * dloc;
        int j    = j0 + jj;
        const float* scp = jj ? sc1 : sc0;

        const float* vpb = vp + (size_t)b * 131072;
        float4 ao = make_float4(0.f, 0.f, 0.f, 0.f);
        #pragma unroll 4
        for (int i = 0; i < 128; i++) {
            float4 v = *(const float4*)(vpb + (size_t)i * 1024 + dd);
            float f = scp[i];
            ao.x += f * v.x; ao.y += f * v.y; ao.z += f * v.z; ao.w += f * v.w;
        }
        float4 s = *(const float4*)(sp + (size_t)j * 1024 + dd);
        float4 o;
        o.x = silu_f(ao.x * s.x);
        o.y = silu_f(ao.y * s.y);
        o.z = silu_f(ao.z * s.z);
        o.w = silu_f(ao.w * s.w);
        *(float4*)(O + ((size_t)b * 128 + j) * 1024 + dd) = o;
    }
}

extern "C" void kernel_launch(void* const* d_in, const int* in_sizes, int n_in,
                              void* d_out, int out_size, void* d_ws, size_t ws_size,
                              hipStream_t stream) {
    const float* values  = (const float*)d_in[0];
    const float* symbols = (const float*)d_in[1];
    const float* conv1_w = (const float*)d_in[2];
    const float* conv1_b = (const float*)d_in[3];
    const float* ln1_g   = (const float*)d_in[4];
    const float* ln1_b   = (const float*)d_in[5];
    const float* conv2_w = (const float*)d_in[6];
    const float* conv2_b = (const float*)d_in[7];
    const float* ln2_g   = (const float*)d_in[8];
    const float* ln2_b   = (const float*)d_in[9];

    float* out = (float*)d_out;
    float* O   = out;                       // (4,128,1024)
    float* vp  = out + 4 * 128 * 1024;      // (4,128,1024)

    float* sp  = (float*)d_ws;              // (128,1024) f32
    short* h1  = (short*)(sp + 128 * 1024); // (3200,128) bf16
    short* w1s = h1 + 3200 * 128;           // 327,680
    short* w2s = w1s + 327680;              // 393,216

    k_prep<<<2816, 256, 0, stream>>>(conv1_w, conv2_w, w1s, w2s);
    k_conv1m<<<200, 256, 0, stream>>>(values, symbols, w1s,
                                      conv1_b, ln1_g, ln1_b, h1);
    k_conv2m<<<40, 256, 0, stream>>>(h1, w2s, conv2_b, ln2_g, ln2_b, vp, sp);
    k_attn<<<256, 512, 0, stream>>>(vp, sp, O);
}

// Round 15
// 174.302 us; speedup vs baseline: 1.0423x; 1.0423x over previous
//
#include <hip/hip_runtime.h>
#include <math.h>

#define LN_EPS 1e-3f

typedef __attribute__((ext_vector_type(8))) short short8;
typedef __attribute__((ext_vector_type(4))) float floatx4;

__device__ __forceinline__ float silu_f(float x) { return x / (1.f + expf(-x)); }

__device__ __forceinline__ int mism1(float a, float s) {
    unsigned ua = __float_as_uint(a);
    unsigned ub = __float_as_uint(a + s);
    return (int)((ua ^ ub) >> 31);
}

__device__ __forceinline__ short f2bf(float f) {
    unsigned u = __float_as_uint(f);
    unsigned r = (u + 0x7FFFu + ((u >> 16) & 1u)) >> 16;
    return (short)r;
}

// ---------------- Kernel 0: swizzle conv1 + conv2 weights into B-fragment bf16
// w1s[kc(8)][ks(10)][nt(8)][lane(64)][j(8)]  (327,680)
// w2s[ks(12)][nt(64)][lane(64)][j(8)]        (393,216)
__global__ __launch_bounds__(256) void k_prep(
    const float* __restrict__ w1,   // (5,512,128)
    const float* __restrict__ w2,   // (3,128,1024)
    short* __restrict__ w1s,
    short* __restrict__ w2s)
{
    int tid = blockIdx.x * 256 + threadIdx.x;
    if (tid < 327680) {
        int j    = tid & 7;
        int lane = (tid >> 3) & 63;
        int nt   = (tid >> 9) & 7;
        int ks   = (tid >> 12) % 10;
        int kc   = tid / 40960;
        int kw = ks >> 1;
        int ci = kc * 64 + (ks & 1) * 32 + ((lane >> 4) & 3) * 8 + j;
        int n  = nt * 16 + (lane & 15);
        w1s[tid] = f2bf(w1[((size_t)(kw * 512 + ci)) * 128 + n]);
    } else {
        int t = tid - 327680;
        if (t < 393216) {
            int j    = t & 7;
            int lane = (t >> 3) & 63;
            int nt   = (t >> 9) & 63;
            int ks   = t >> 15;                 // 0..11
            int k  = ks * 32 + ((lane >> 4) & 3) * 8 + j;   // 0..383
            int kw = k >> 7;
            int ci = k & 127;
            int n  = nt * 16 + (lane & 15);
            w2s[t] = f2bf(w2[((size_t)(kw * 128 + ci)) * 1024 + n]);
        }
    }
}

// ---------------- Kernel 1: conv1 MFMA + bias + LN1(128) + SiLU -> h1 bf16
// grid = 200 blocks (16 pos each), 256 threads (4 waves, 2 n-tiles each).
// NOTE: single-buffered staging on purpose — explicit double-buffering
// regressed (R14: 172->182 us; cf. learn_hip m99/m100).
__global__ __launch_bounds__(256) void k_conv1m(
    const float* __restrict__ values,   // (4,1920,512)
    const float* __restrict__ symbols,  // (1920,512)
    const short* __restrict__ w1s,
    const float* __restrict__ b1,
    const float* __restrict__ g1,
    const float* __restrict__ bt1,
    short* __restrict__ h1)             // (3200,128) bf16
{
    int mt  = blockIdx.x;               // 0..199
    int seq = mt / 40;
    int tl  = mt % 40;
    const float* x = (seq < 4) ? (values + (size_t)seq * 1920 * 512) : symbols;
    int p0 = 3 * (tl * 16) - 1;

    __shared__ short xs[50 * 72];
    __shared__ float red[4][4][4][2];

    int tid  = threadIdx.x;
    int lane = tid & 63, w = tid >> 6;
    int quad = lane >> 4, mrow = lane & 15;

    floatx4 acc[2];
    acc[0] = (floatx4){0.f, 0.f, 0.f, 0.f};
    acc[1] = (floatx4){0.f, 0.f, 0.f, 0.f};

    for (int kc = 0; kc < 8; kc++) {
        __syncthreads();
        for (int idx = tid; idx < 50 * 16; idx += 256) {
            int r = idx >> 4, g = idx & 15;
            int gp = p0 + r;
            float4 v = make_float4(0.f, 0.f, 0.f, 0.f);
            if (gp >= 0 && gp < 1920)
                v = *(const float4*)(x + (size_t)gp * 512 + kc * 64 + 4 * g);
            short* d = xs + r * 72 + 4 * g;
            d[0] = f2bf(v.x); d[1] = f2bf(v.y); d[2] = f2bf(v.z); d[3] = f2bf(v.w);
        }
        __syncthreads();

        #pragma unroll
        for (int ks = 0; ks < 10; ks++) {
            int kw  = ks >> 1;
            int ci0 = (ks & 1) * 32;
            short8 a = *(const short8*)(xs + (3 * mrow + kw) * 72 + ci0 + quad * 8);
            #pragma unroll
            for (int ni = 0; ni < 2; ni++) {
                short8 b = *(const short8*)(w1s +
                    ((((size_t)kc * 10 + ks) * 8 + (w * 2 + ni)) * 64 + lane) * 8);
                acc[ni] = __builtin_amdgcn_mfma_f32_16x16x32_bf16(a, b, acc[ni], 0, 0, 0);
            }
        }
    }

    float b1v[2], g1v[2], btv[2];
    #pragma unroll
    for (int ni = 0; ni < 2; ni++) {
        int co = w * 32 + ni * 16 + mrow;
        b1v[ni] = b1[co]; g1v[ni] = g1[co]; btv[ni] = bt1[co];
    }

    float s1[4] = {0.f, 0.f, 0.f, 0.f}, s2[4] = {0.f, 0.f, 0.f, 0.f};
    #pragma unroll
    for (int ni = 0; ni < 2; ni++)
        #pragma unroll
        for (int r = 0; r < 4; r++) {
            float v = acc[ni][r] + b1v[ni];
            acc[ni][r] = v;
            s1[r] += v; s2[r] += v * v;
        }
    #pragma unroll
    for (int m = 8; m >= 1; m >>= 1) {
        #pragma unroll
        for (int r = 0; r < 4; r++) {
            s1[r] += __shfl_xor(s1[r], m, 64);
            s2[r] += __shfl_xor(s2[r], m, 64);
        }
    }
    if (mrow == 0) {
        #pragma unroll
        for (int r = 0; r < 4; r++) { red[w][quad][r][0] = s1[r]; red[w][quad][r][1] = s2[r]; }
    }
    __syncthreads();

    #pragma unroll
    for (int r = 0; r < 4; r++) {
        float S1 = red[0][quad][r][0] + red[1][quad][r][0]
                 + red[2][quad][r][0] + red[3][quad][r][0];
        float S2 = red[0][quad][r][1] + red[1][quad][r][1]
                 + red[2][quad][r][1] + red[3][quad][r][1];
        float mean = S1 * (1.f / 128.f);
        float var  = S2 * (1.f / 128.f) - mean * mean;
        float rs   = rsqrtf(var + LN_EPS);
        int row = seq * 640 + tl * 16 + quad * 4 + r;
        #pragma unroll
        for (int ni = 0; ni < 2; ni++) {
            float o = silu_f((acc[ni][r] - mean) * rs * g1v[ni] + btv[ni]);
            h1[(size_t)row * 128 + w * 32 + ni * 16 + mrow] = f2bf(o);
        }
    }
}

// ---------------- Kernel 2: conv2 MFMA (16 pos x 1024 co) + LN2 + SiLU -> vp/sp
// grid = 40 blocks, 256 threads (4 waves, 16 n-tiles each).
__global__ __launch_bounds__(256) void k_conv2m(
    const short* __restrict__ h1,    // (3200,128) bf16
    const short* __restrict__ w2s,
    const float* __restrict__ b2,
    const float* __restrict__ g2,
    const float* __restrict__ bt2,
    float* __restrict__ vp,          // (512,1024)
    float* __restrict__ sp)          // (128,1024)
{
    int blk  = blockIdx.x;           // 0..39
    int pos0 = blk * 16;
    int seq  = pos0 >> 7;
    int lcl0 = pos0 & 127;
    int row0 = seq * 640 + 5 * lcl0;

    __shared__ short xa[78 * 136];
    __shared__ float red[4][4][4][2];

    int tid = threadIdx.x;
    int lane = tid & 63, w = tid >> 6;
    int quad = lane >> 4, mrow = lane & 15;

    for (int idx = tid; idx < 78 * 16; idx += 256) {
        int r = idx >> 4, g = idx & 15;
        *(short8*)(xa + r * 136 + g * 8) =
            *(const short8*)(h1 + (size_t)(row0 + r) * 128 + g * 8);
    }
    __syncthreads();

    floatx4 acc[16];
    #pragma unroll
    for (int nt = 0; nt < 16; nt++) acc[nt] = (floatx4){0.f, 0.f, 0.f, 0.f};

    #pragma unroll 3
    for (int ks = 0; ks < 12; ks++) {
        int kw  = ks >> 2;
        int ci0 = (ks & 3) * 32;
        short8 a = *(const short8*)(xa + (5 * mrow + kw) * 136 + ci0 + quad * 8);
        #pragma unroll
        for (int nt = 0; nt < 16; nt++) {
            short8 b = *(const short8*)(w2s +
                (((size_t)ks * 64 + w * 16 + nt) * 64 + lane) * 8);
            acc[nt] = __builtin_amdgcn_mfma_f32_16x16x32_bf16(a, b, acc[nt], 0, 0, 0);
        }
    }

    float b2v[16], g2v[16], btv[16];
    #pragma unroll
    for (int nt = 0; nt < 16; nt++) {
        int co = w * 256 + nt * 16 + mrow;
        b2v[nt] = b2[co]; g2v[nt] = g2[co]; btv[nt] = bt2[co];
    }

    float s1[4] = {0.f, 0.f, 0.f, 0.f}, s2[4] = {0.f, 0.f, 0.f, 0.f};
    #pragma unroll
    for (int nt = 0; nt < 16; nt++)
        #pragma unroll
        for (int r = 0; r < 4; r++) {
            float v = acc[nt][r] + b2v[nt];
            acc[nt][r] = v;
            s1[r] += v; s2[r] += v * v;
        }
    #pragma unroll
    for (int m = 8; m >= 1; m >>= 1) {
        #pragma unroll
        for (int r = 0; r < 4; r++) {
            s1[r] += __shfl_xor(s1[r], m, 64);
            s2[r] += __shfl_xor(s2[r], m, 64);
        }
    }
    if (mrow == 0) {
        #pragma unroll
        for (int r = 0; r < 4; r++) { red[w][quad][r][0] = s1[r]; red[w][quad][r][1] = s2[r]; }
    }
    __syncthreads();

    float mean[4], rs[4];
    #pragma unroll
    for (int r = 0; r < 4; r++) {
        float S1 = red[0][quad][r][0] + red[1][quad][r][0]
                 + red[2][quad][r][0] + red[3][quad][r][0];
        float S2 = red[0][quad][r][1] + red[1][quad][r][1]
                 + red[2][quad][r][1] + red[3][quad][r][1];
        mean[r] = S1 * (1.f / 1024.f);
        float var = S2 * (1.f / 1024.f) - mean[r] * mean[r];
        rs[r] = rsqrtf(var + LN_EPS);
    }

    float* obase = (pos0 < 512) ? (vp + (size_t)pos0 * 1024)
                                : (sp + (size_t)(pos0 - 512) * 1024);
    #pragma unroll
    for (int nt = 0; nt < 16; nt++) {
        int co = w * 256 + nt * 16 + mrow;
        #pragma unroll
        for (int r = 0; r < 4; r++) {
            float o = silu_f((acc[nt][r] - mean[r]) * rs[r] * g2v[nt] + btv[nt]);
            obase[((size_t)(quad * 4 + r)) * 1024 + co] = o;
        }
    }
}

// ---------------- Kernel 3: fused attention (counts + softmax + einsum + SiLU)
// grid = 4b * 64 jpair = 256 blocks, 512 threads (8 waves).
// softmax: S in [-1,1] so exp(S) is safe without max subtraction.
__global__ __launch_bounds__(512) void k_attn(
    const float* __restrict__ vp,   // (512,1024)
    const float* __restrict__ sp,   // (128,1024)
    float* __restrict__ O)          // (4,128,1024)
{
    int b  = blockIdx.x >> 6;
    int j0 = (blockIdx.x & 63) * 2;
    int tid = threadIdx.x, lane = tid & 63, wv = tid >> 6;

    __shared__ int   cc[4][128][2];
    __shared__ float sc0[128], sc1[128];
    __shared__ float reds[2][8];

    // phase A: mismatch counts; thread = (i = tid&127, sub = tid>>7 covers 256 d)
    {
        int i = tid & 127, sub = tid >> 7;
        int d0 = sub * 256;
        const float* vrow = vp + ((size_t)(b * 128 + i)) * 1024 + d0;
        const float* s0r  = sp + (size_t)j0 * 1024 + d0;
        const float* s1r  = s0r + 1024;
        int m0 = 0, m1 = 0;
        #pragma unroll 8
        for (int k = 0; k < 64; k++) {
            float4 v  = *(const float4*)(vrow + 4 * k);
            float4 s0 = *(const float4*)(s0r + 4 * k);
            float4 s1 = *(const float4*)(s1r + 4 * k);
            m0 += mism1(v.x, s0.x) + mism1(v.y, s0.y) + mism1(v.z, s0.z) + mism1(v.w, s0.w);
            m1 += mism1(v.x, s1.x) + mism1(v.y, s1.y) + mism1(v.z, s1.z) + mism1(v.w, s1.w);
        }
        cc[sub][i][0] = m0;
        cc[sub][i][1] = m1;
    }
    __syncthreads();

    // phase B: softmax over i=128 for both j's, no max subtraction (S in [-1,1])
    float e0 = 0.f, e1 = 0.f;
    if (tid < 128) {
        int c0 = cc[0][tid][0] + cc[1][tid][0] + cc[2][tid][0] + cc[3][tid][0];
        int c1 = cc[0][tid][1] + cc[1][tid][1] + cc[2][tid][1] + cc[3][tid][1];
        e0 = expf(1.f - (float)c0 * (2.f / 1024.f));
        e1 = expf(1.f - (float)c1 * (2.f / 1024.f));
    }
    float t0 = e0, t1 = e1;
    #pragma unroll
    for (int m = 32; m >= 1; m >>= 1) {
        t0 += __shfl_xor(t0, m, 64);
        t1 += __shfl_xor(t1, m, 64);
    }
    if (lane == 0) { reds[0][wv] = t0; reds[1][wv] = t1; }
    __syncthreads();
    float tot0 = reds[0][0] + reds[0][1];
    float tot1 = reds[1][0] + reds[1][1];
    if (tid < 128) { sc0[tid] = e0 / tot0; sc1[tid] = e1 / tot1; }
    __syncthreads();

    // phase C: einsum + SiLU; thread = (jj = tid>>8, dloc = tid&255)
    {
        int jj   = tid >> 8;
        int dloc = tid & 255;
        int dd   = 4 * dloc;
        int j    = j0 + jj;
        const float* scp = jj ? sc1 : sc0;

        const float* vpb = vp + (size_t)b * 131072;
        float4 ao = make_float4(0.f, 0.f, 0.f, 0.f);
        #pragma unroll 4
        for (int i = 0; i < 128; i++) {
            float4 v = *(const float4*)(vpb + (size_t)i * 1024 + dd);
            float f = scp[i];
            ao.x += f * v.x; ao.y += f * v.y; ao.z += f * v.z; ao.w += f * v.w;
        }
        float4 s = *(const float4*)(sp + (size_t)j * 1024 + dd);
        float4 o;
        o.x = silu_f(ao.x * s.x);
        o.y = silu_f(ao.y * s.y);
        o.z = silu_f(ao.z * s.z);
        o.w = silu_f(ao.w * s.w);
        *(float4*)(O + ((size_t)b * 128 + j) * 1024 + dd) = o;
    }
}

extern "C" void kernel_launch(void* const* d_in, const int* in_sizes, int n_in,
                              void* d_out, int out_size, void* d_ws, size_t ws_size,
                              hipStream_t stream) {
    const float* values  = (const float*)d_in[0];
    const float* symbols = (const float*)d_in[1];
    const float* conv1_w = (const float*)d_in[2];
    const float* conv1_b = (const float*)d_in[3];
    const float* ln1_g   = (const float*)d_in[4];
    const float* ln1_b   = (const float*)d_in[5];
    const float* conv2_w = (const float*)d_in[6];
    const float* conv2_b = (const float*)d_in[7];
    const float* ln2_g   = (const float*)d_in[8];
    const float* ln2_b   = (const float*)d_in[9];

    float* out = (float*)d_out;
    float* O   = out;                       // (4,128,1024)
    float* vp  = out + 4 * 128 * 1024;      // (4,128,1024)

    float* sp  = (float*)d_ws;              // (128,1024) f32
    short* h1  = (short*)(sp + 128 * 1024); // (3200,128) bf16
    short* w1s = h1 + 3200 * 128;           // 327,680
    short* w2s = w1s + 327680;              // 393,216

    k_prep<<<2816, 256, 0, stream>>>(conv1_w, conv2_w, w1s, w2s);
    k_conv1m<<<200, 256, 0, stream>>>(values, symbols, w1s,
                                      conv1_b, ln1_g, ln1_b, h1);
    k_conv2m<<<40, 256, 0, stream>>>(h1, w2s, conv2_b, ln2_g, ln2_b, vp, sp);
    k_attn<<<256, 512, 0, stream>>>(vp, sp, O);
}